// Round 4
// baseline (75.635 us; speedup 1.0000x reference)
//
#include <hip/hip_runtime.h>
#include <cstdint>
#include <cstddef>

typedef __bf16 bf16x8 __attribute__((ext_vector_type(8)));
typedef float  f32x4  __attribute__((ext_vector_type(4)));

#define N_ROWS 8192
#define KDIM   256
#define TEMP_INV 2.0f
#define LOG2E  1.4426950408889634f
#define EXPC   (TEMP_INV * LOG2E)

__device__ __forceinline__ ushort f2bf(float x) {
    uint32_t u = __float_as_uint(x);
    u += 0x7fffu + ((u >> 16) & 1u);
    return (ushort)(u >> 16);
}

// ---------------- Kernel A: label ranking / permutation (1 block, deterministic)
__global__ void build_perm(const int* __restrict__ label, int* __restrict__ perm,
                           int* __restrict__ labelPerm, int* __restrict__ classStart,
                           int* __restrict__ cumTiles)
{
    __shared__ int lcnt[256][10];
    __shared__ int cstart[11];
    __shared__ int ccount[10];
    const int tid = threadIdx.x;
    const int wave = tid >> 6, lane = tid & 63;
    const int beg = tid * 32, end = beg + 32;

    int loc[10] = {0,0,0,0,0,0,0,0,0,0};
    for (int i = beg; i < end; ++i) {
        int c = label[i]; c = (c < 0) ? 0 : (c > 9 ? 9 : c);
        loc[c]++;
    }
    #pragma unroll
    for (int c = 0; c < 10; ++c) lcnt[tid][c] = loc[c];
    __syncthreads();

    for (int c = wave; c < 10; c += 4) {
        int s0 = lcnt[lane*4+0][c], s1 = lcnt[lane*4+1][c];
        int s2 = lcnt[lane*4+2][c], s3 = lcnt[lane*4+3][c];
        int tot = s0 + s1 + s2 + s3;
        int incl = tot;
        #pragma unroll
        for (int d = 1; d < 64; d <<= 1) {
            int up = __shfl_up(incl, d, 64);
            if (lane >= d) incl += up;
        }
        int excl = incl - tot;
        lcnt[lane*4+0][c] = excl;
        lcnt[lane*4+1][c] = excl + s0;
        lcnt[lane*4+2][c] = excl + s0 + s1;
        lcnt[lane*4+3][c] = excl + s0 + s1 + s2;
        if (lane == 63) ccount[c] = incl;
    }
    __syncthreads();

    if (tid == 0) {
        int run = 0, runT = 0;
        for (int c = 0; c < 10; ++c) {
            cstart[c] = run; classStart[c] = run;
            int tpc = (ccount[c] + 127) >> 7;
            cumTiles[c] = runT;
            run  += ccount[c];
            runT += tpc * tpc;
        }
        cstart[10] = run; classStart[10] = run; cumTiles[10] = runT;
    }
    __syncthreads();

    int ofs[10];
    #pragma unroll
    for (int c = 0; c < 10; ++c) ofs[c] = lcnt[tid][c];
    for (int i = beg; i < end; ++i) {
        int c = label[i]; c = (c < 0) ? 0 : (c > 9 ? 9 : c);
        int pos = cstart[c] + ofs[c]++;
        perm[pos] = i;
        labelPerm[pos] = c;
    }
}

// ---------------- Kernel B: normalize + permute + bf16 cast (4 rows / block)
__global__ __launch_bounds__(256) void normalize_rows(const float* __restrict__ logits,
        const int* __restrict__ perm, ushort* __restrict__ xn)
{
    const int p = blockIdx.x * 4 + (threadIdx.x >> 6);
    const int lane = threadIdx.x & 63;
    const int old = perm[p];
    float4 v = reinterpret_cast<const float4*>(logits + (size_t)old * KDIM)[lane];
    float ss = v.x*v.x + v.y*v.y + v.z*v.z + v.w*v.w;
    #pragma unroll
    for (int off = 32; off >= 1; off >>= 1) ss += __shfl_xor(ss, off, 64);
    float inv = 1.0f / fmaxf(sqrtf(ss), 1e-8f);
    ushort4 o;
    o.x = f2bf(v.x * inv); o.y = f2bf(v.y * inv);
    o.z = f2bf(v.z * inv); o.w = f2bf(v.w * inv);
    reinterpret_cast<ushort4*>(xn + (size_t)p * KDIM)[lane] = o;
}

// ---------------- shared GEMM core: 128x128 tile, BK=64, 4 waves, T2-swizzled
// LDS chunk swizzle (rule #21): stored chunk cs = c ^ (row&7); linear LDS dest,
// pre-swizzled GLOBAL source, same XOR on ds_read.
__device__ __forceinline__ void stage_tiles(const ushort* __restrict__ xn,
        int rowBase, int colBase, int kb, ushort* As, ushort* Bs, int wave, int lane)
{
    #pragma unroll
    for (int it = 0; it < 4; ++it) {
        int ci = it * 256 + wave * 64 + lane;          // 16B chunk index in [0,1024)
        int row = ci >> 3;
        int c = (ci & 7) ^ (row & 7);                  // logical chunk for this slot
        int rowA = rowBase + row; if (rowA > N_ROWS - 1) rowA = N_ROWS - 1;
        int rowB = colBase + row; if (rowB > N_ROWS - 1) rowB = N_ROWS - 1;
        const ushort* gA = xn + (size_t)rowA * KDIM + kb + c * 8;
        const ushort* gB = xn + (size_t)rowB * KDIM + kb + c * 8;
        ushort* lA = As + (size_t)(it * 256 + wave * 64) * 8;  // wave-uniform LDS base
        ushort* lB = Bs + (size_t)(it * 256 + wave * 64) * 8;
        __builtin_amdgcn_global_load_lds((const __attribute__((address_space(1))) void*)gA,
                                         (__attribute__((address_space(3))) void*)lA, 16, 0, 0);
        __builtin_amdgcn_global_load_lds((const __attribute__((address_space(1))) void*)gB,
                                         (__attribute__((address_space(3))) void*)lB, 16, 0, 0);
    }
}

__device__ __forceinline__ void read_frags(const ushort* As, const ushort* Bs,
        bf16x8 (&a)[2][4], bf16x8 (&b)[2][4], int wave, int lane)
{
    const int wr = wave >> 1, wc = wave & 1;
    const int lrow = lane & 15, kgrp = lane >> 4;
    #pragma unroll
    for (int kk = 0; kk < 2; ++kk) {
        const int c = kk * 4 + kgrp;                   // logical 16B chunk
        #pragma unroll
        for (int mi = 0; mi < 4; ++mi) {
            const int row = wr*64 + mi*16 + lrow;
            a[kk][mi] = *reinterpret_cast<const bf16x8*>(As + (size_t)row * 64 + ((c ^ (row & 7)) * 8));
        }
        #pragma unroll
        for (int ni = 0; ni < 4; ++ni) {
            const int row = wc*64 + ni*16 + lrow;
            b[kk][ni] = *reinterpret_cast<const bf16x8*>(Bs + (size_t)row * 64 + ((c ^ (row & 7)) * 8));
        }
    }
}

__device__ __forceinline__ void mfma_frags(bf16x8 (&a)[2][4], bf16x8 (&b)[2][4],
                                           f32x4 (&acc)[4][4])
{
    #pragma unroll
    for (int kk = 0; kk < 2; ++kk)
        #pragma unroll
        for (int mi = 0; mi < 4; ++mi)
            #pragma unroll
            for (int ni = 0; ni < 4; ++ni)
                acc[mi][ni] = __builtin_amdgcn_mfma_f32_16x16x32_bf16(a[kk][mi], b[kk][ni], acc[mi][ni], 0, 0, 0);
}

// T3/T4-style pipelined K-loop: raw barriers, counted vmcnt (never 0 mid-loop).
// Per step: reads -> lgkm0+BAR (read-release) -> stage into freed buf -> MFMA
// (T5 setprio) -> vmcnt(8) (next buf's loads landed; own stage stays in
// flight) -> BAR. sched_barrier(0) pins the reads before the release (rule #18).
#define PIPE_READS_RELEASE(Ac, Bc)                                   \
    bf16x8 a[2][4], b[2][4];                                         \
    read_frags(Ac, Bc, a, b, wave, lane);                            \
    __builtin_amdgcn_sched_barrier(0);                               \
    asm volatile("s_waitcnt lgkmcnt(0)" ::: "memory");               \
    __builtin_amdgcn_s_barrier();

#define PIPE_MFMA()                                                  \
    __builtin_amdgcn_s_setprio(1);                                   \
    mfma_frags(a, b, acc);                                           \
    __builtin_amdgcn_s_setprio(0);

#define PIPE_TAIL(N)                                                 \
    __builtin_amdgcn_sched_barrier(0);                               \
    asm volatile("s_waitcnt vmcnt(" #N ")" ::: "memory");            \
    __builtin_amdgcn_s_barrier();

__device__ __forceinline__ void kloop_pipe(const ushort* __restrict__ xn,
        int rowBase, int colBase, f32x4 (&acc)[4][4],
        ushort* As0, ushort* Bs0, ushort* As1, ushort* Bs1, int wave, int lane)
{
    stage_tiles(xn, rowBase, colBase, 0,  As0, Bs0, wave, lane);   // S0: 8 loads
    stage_tiles(xn, rowBase, colBase, 64, As1, Bs1, wave, lane);   // S1: 8 loads
    asm volatile("s_waitcnt vmcnt(8)" ::: "memory");               // S0 landed
    __builtin_amdgcn_s_barrier();
    { // kt0: compute b0, stage S2->b0
        PIPE_READS_RELEASE(As0, Bs0)
        stage_tiles(xn, rowBase, colBase, 128, As0, Bs0, wave, lane);
        PIPE_MFMA()
        PIPE_TAIL(8)                                               // S1 landed
    }
    { // kt1: compute b1, stage S3->b1
        PIPE_READS_RELEASE(As1, Bs1)
        stage_tiles(xn, rowBase, colBase, 192, As1, Bs1, wave, lane);
        PIPE_MFMA()
        PIPE_TAIL(8)                                               // S2 landed
    }
    { // kt2: compute b0
        PIPE_READS_RELEASE(As0, Bs0)
        PIPE_MFMA()
        PIPE_TAIL(0)                                               // S3 landed
    }
    { // kt3: compute b1 (release barrier inside frees LDS for epilogue aliasing)
        PIPE_READS_RELEASE(As1, Bs1)
        PIPE_MFMA()
    }
}

// ---------------- Kernel C: upper-triangular tiles (bi<=bj), accumulate ONLY
// D-partials (sum of diff-label e). Off-diagonal tiles also emit column
// partials via e_ij == e_ji symmetry. Diagonal term auto-excluded (same label).
__global__ __launch_bounds__(256) void phase1_gemm(const ushort* __restrict__ xn,
        const int* __restrict__ labelPerm, float* __restrict__ pD)
{
    __shared__ __align__(16) char pool[65536];
    ushort* As0 = (ushort*)(pool);
    ushort* Bs0 = (ushort*)(pool + 16384);
    ushort* As1 = (ushort*)(pool + 32768);
    ushort* Bs1 = (ushort*)(pool + 49152);
    float* rowD = (float*)(pool);            // [128][32] f32, aliases buf0 (safe post-release)
    float* colD = (float*)(pool + 16384);    // [128][8]  f32
    __shared__ int labLDS[256];              // [0:128) row labels, [128:256) col labels

    const int tid = threadIdx.x;
    const int wave = tid >> 6, lane = tid & 63;

    int t = blockIdx.x, bi = 0;
    while (t >= 64 - bi) { t -= 64 - bi; ++bi; }
    const int bj = bi + t;
    const bool isDiag = (bi == bj);
    const int rowBase = bi * 128, colBase = bj * 128;

    // label load + LDS write BEFORE staging (keeps vmcnt counting clean)
    labLDS[tid] = labelPerm[(tid < 128) ? (rowBase + tid) : (colBase + tid - 128)];
    __builtin_amdgcn_sched_barrier(0);

    f32x4 acc[4][4] = {};
    kloop_pipe(xn, rowBase, colBase, acc, As0, Bs0, As1, Bs1, wave, lane);

    // ---- epilogue: exp + diff-label mask, LDS-based reductions
    const int wr = wave >> 1, wc = wave & 1;
    const int lrow = lane & 15, lgrp = lane >> 4;
    float colAcc[4] = {0.f, 0.f, 0.f, 0.f};
    #pragma unroll
    for (int mi = 0; mi < 4; ++mi) {
        #pragma unroll
        for (int reg = 0; reg < 4; ++reg) {
            const int tr = wr * 64 + mi * 16 + lgrp * 4 + reg;
            const int rl = labLDS[tr];
            float rowAcc = 0.f;
            #pragma unroll
            for (int ni = 0; ni < 4; ++ni) {
                const int tc = wc * 64 + ni * 16 + lrow;
                float e = __builtin_amdgcn_exp2f(acc[mi][ni][reg] * EXPC);
                float ed = (rl != labLDS[128 + tc]) ? e : 0.f;
                rowAcc += ed;
                colAcc[ni] += ed;
            }
            rowD[tr * 32 + wc * 16 + lrow] = rowAcc;
        }
    }
    if (!isDiag) {
        #pragma unroll
        for (int ni = 0; ni < 4; ++ni) {
            const int tc = wc * 64 + ni * 16 + lrow;
            colD[tc * 8 + wr * 4 + lgrp] = colAcc[ni];
        }
    }
    __syncthreads();

    if (tid < 128) {
        const float* p = rowD + tid * 32;
        float s = 0.f;
        #pragma unroll
        for (int k = 0; k < 8; ++k) {
            f32x4 v = *reinterpret_cast<const f32x4*>(p + k * 4);
            s += v[0] + v[1] + v[2] + v[3];
        }
        pD[(size_t)bj * N_ROWS + rowBase + tid] = s;
    } else if (!isDiag) {
        const int c2 = tid - 128;
        const float* p = colD + c2 * 8;
        f32x4 v0 = *reinterpret_cast<const f32x4*>(p);
        f32x4 v1 = *reinterpret_cast<const f32x4*>(p + 4);
        pD[(size_t)bi * N_ROWS + colBase + c2] =
            v0[0] + v0[1] + v0[2] + v0[3] + v1[0] + v1[1] + v1[2] + v1[3];
    }
}

// ---------------- Kernel C2: D_i = sum of 64 slices (deterministic fixed order)
__global__ void phase2_rowsum(const float* __restrict__ pD, float* __restrict__ Darr)
{
    const int i = blockIdx.x * blockDim.x + threadIdx.x;
    if (i >= N_ROWS) return;
    float d = 0.f;
    for (int tj = 0; tj < 64; ++tj) d += pD[(size_t)tj * N_ROWS + i];
    Darr[i] = d;
}

// ---------------- Kernel D: same-class diagonal block tiles -> log terms
__global__ __launch_bounds__(256) void phase3_loss(const ushort* __restrict__ xn,
        const float* __restrict__ Darr, const int* __restrict__ classStart,
        const int* __restrict__ cumTiles, float* __restrict__ partial)
{
    __shared__ __align__(16) char pool[65536];
    ushort* As0 = (ushort*)(pool);
    ushort* Bs0 = (ushort*)(pool + 16384);
    ushort* As1 = (ushort*)(pool + 32768);
    ushort* Bs1 = (ushort*)(pool + 49152);
    __shared__ float red[256];

    const int b = blockIdx.x;
    const int nTiles = cumTiles[10];
    if (b >= nTiles) return;

    int c = 0;
    while (c < 9 && b >= cumTiles[c + 1]) ++c;
    const int s = classStart[c], e = classStart[c + 1];
    const int nc = e - s;
    const int tps = (nc + 127) >> 7;
    const int lt = b - cumTiles[c];
    const int ti = lt / tps, tj = lt - ti * tps;
    const int rowBase = s + ti * 128, colBase = s + tj * 128;

    const int tid = threadIdx.x;
    const int wave = tid >> 6, lane = tid & 63;

    f32x4 acc[4][4] = {};
    kloop_pipe(xn, rowBase, colBase, acc, As0, Bs0, As1, Bs1, wave, lane);

    const int wr = wave >> 1, wc = wave & 1;
    const int lrow = lane & 15, lgrp = lane >> 4;
    float lsum = 0.f;
    #pragma unroll
    for (int mi = 0; mi < 4; ++mi) {
        #pragma unroll
        for (int reg = 0; reg < 4; ++reg) {
            const int r = rowBase + wr * 64 + mi * 16 + lgrp * 4 + reg;
            if (r < e) {
                const float Dr = Darr[r];
                #pragma unroll
                for (int ni = 0; ni < 4; ++ni) {
                    const int cg = colBase + wc * 64 + ni * 16 + lrow;
                    if (cg < e && cg != r) {
                        float sim = acc[mi][ni][reg];
                        float ev = __builtin_amdgcn_exp2f(sim * EXPC);
                        lsum += __logf(ev + Dr) - TEMP_INV * sim;
                    }
                }
            }
        }
    }
    red[tid] = lsum;
    __syncthreads();
    for (int st = 128; st > 0; st >>= 1) {
        if (tid < st) red[tid] += red[tid + st];
        __syncthreads();
    }
    if (tid == 0) partial[b] = red[0];
}

// ---------------- Kernel E: deterministic final reduction + scale
__global__ void phase4_final(const float* __restrict__ partial, const int* __restrict__ cumTiles,
                             float* __restrict__ out)
{
    __shared__ float red[256];
    const int tid = threadIdx.x;
    const int nTiles = cumTiles[10];
    float s = 0.f;
    for (int i = tid; i < nTiles; i += 256) s += partial[i];
    red[tid] = s;
    __syncthreads();
    for (int st = 128; st > 0; st >>= 1) {
        if (tid < st) red[tid] += red[tid + st];
        __syncthreads();
    }
    if (tid == 0) out[0] = red[0] * (1.0f / 16384.0f);
}

extern "C" void kernel_launch(void* const* d_in, const int* in_sizes, int n_in,
                              void* d_out, int out_size, void* d_ws, size_t ws_size,
                              hipStream_t stream)
{
    const float* logits = (const float*)d_in[0];
    const int*   label  = (const int*)d_in[1];
    float* out = (float*)d_out;

    char* ws = (char*)d_ws;
    ushort* xn        = (ushort*)(ws);                          // 4 MB
    float*  pD        = (float*)(ws + (4u << 20));              // 2 MB
    float*  Darr      = (float*)(ws + (6u << 20));              // 32 KB
    int*    perm      = (int*)(ws + (6u << 20) + (64u << 10));  // 32 KB
    int*    labelPerm = (int*)(ws + (6u << 20) + (128u << 10)); // 32 KB
    int*    classStart= (int*)(ws + (6u << 20) + (192u << 10)); // 64 B
    int*    cumTiles  = (int*)(ws + (6u << 20) + (192u << 10) + 256); // 64 B
    float*  partial   = (float*)(ws + (6u << 20) + (256u << 10));     // 16 KB

    hipLaunchKernelGGL(build_perm, dim3(1), dim3(256), 0, stream,
                       label, perm, labelPerm, classStart, cumTiles);
    hipLaunchKernelGGL(normalize_rows, dim3(2048), dim3(256), 0, stream,
                       logits, perm, xn);
    hipLaunchKernelGGL(phase1_gemm, dim3(2080), dim3(256), 0, stream,
                       xn, labelPerm, pD);
    hipLaunchKernelGGL(phase2_rowsum, dim3(32), dim3(256), 0, stream,
                       pD, Darr);
    hipLaunchKernelGGL(phase3_loss, dim3(4096), dim3(256), 0, stream,
                       xn, Darr, classStart, cumTiles, partial);
    hipLaunchKernelGGL(phase4_final, dim3(1), dim3(256), 0, stream,
                       partial, cumTiles, out);
}